// Round 9
// baseline (467.465 us; speedup 1.0000x reference)
//
#include <hip/hip_runtime.h>
#include <hip/hip_bf16.h>

#define BATCH   32768
#define DIM     2048
#define NHEADS  28
#define NCOLS   280
#define LOSS_SCALE (1.0f / (float)(BATCH * NHEADS))

typedef __attribute__((ext_vector_type(8))) short short8;
typedef __attribute__((ext_vector_type(4))) short s4vec;
typedef __attribute__((ext_vector_type(4))) float f32x4;

__device__ __forceinline__ short f2bf(float f) {
    union { __hip_bfloat16 h; short s; } u; u.h = __float2bfloat16(f); return u.s;
}

// ---------------------------------------------------------------------------
// W pre-swizzle (unchanged from R8)
// ---------------------------------------------------------------------------
__global__ void mvh_swz(const float* __restrict__ W, short* __restrict__ Wswz) {
    int t = blockIdx.x * 256 + threadIdx.x;      // 73728 threads
    int lane = t & 63;
    int ks = (t >> 6) & 63;
    int nt = t >> 12;                            // 0..17
    int n = nt * 16 + (lane & 15);
    int d = ks * 32 + (lane >> 4) * 8;
    short8 v;
    #pragma unroll
    for (int j = 0; j < 8; j++) v[j] = 0;
    if (n < NCOLS) {
        const float* src = W + (size_t)n * DIM + d;
        #pragma unroll
        for (int j = 0; j < 8; j++) v[j] = f2bf(src[j]);
    }
    *(short8*)(Wswz + (size_t)t * 8) = v;
}

// ---------------------------------------------------------------------------
// GEMM — byte-identical to round 8 (142 µs total product path)
// ---------------------------------------------------------------------------
#define A_GRP  16384
#define B_TILE 18432

#define SB0() __builtin_amdgcn_sched_barrier(0)

__global__ __launch_bounds__(512, 4)
void mvh_gemm(const float* __restrict__ hidden, const short* __restrict__ Wswz,
              const float* __restrict__ bias, float* __restrict__ logits) {
    __shared__ __align__(16) char lds[2 * A_GRP + 2 * B_TILE];   // 69632 B
    char* B0 = lds + 2 * A_GRP;
    char* B1 = lds + 2 * A_GRP + B_TILE;

    const int tid  = threadIdx.x;
    const int lane = tid & 63;
    const int wave = tid >> 6;
    const int kph   = wave >> 2;
    const int wsub  = (wave >> 1) & 1;
    const int nhalf = wave & 1;
    const int l15 = lane & 15, lhi = lane >> 4;
    const int rowbase = blockIdx.x * 64;

    const int ar  = tid >> 3;
    const int ak4 = (tid & 7) * 4;
    const float* gAbase = hidden + (size_t)(rowbase + ar) * DIM + ak4;
    const int awbyte = (ar >> 4) * 1024 + ((ar & 15) + 16 * (ak4 >> 3)) * 16 + (ak4 & 4) * 2;

    f32x4 acc0[9], acc1[9];
    #pragma unroll
    for (int n = 0; n < 9; n++) { acc0[n] = (f32x4)0.0f; acc1[n] = (f32x4)0.0f; }

    f32x4 ga0, ga1, ga2, ga3;

#define LOADA4(grp) do { \
    const float* p_ = gAbase + (size_t)(grp) * 128; \
    ga0 = *(const f32x4*)(p_);      ga1 = *(const f32x4*)(p_ + 32); \
    ga2 = *(const f32x4*)(p_ + 64); ga3 = *(const f32x4*)(p_ + 96); \
    SB0(); \
} while (0)

#define WRA1(dst, slot, src) do { \
    s4vec w_; \
    w_[0] = f2bf(src[0]); w_[1] = f2bf(src[1]); w_[2] = f2bf(src[2]); w_[3] = f2bf(src[3]); \
    *(s4vec*)((dst) + (slot) * 4096 + awbyte) = w_; \
} while (0)

#define WRITEA4(dst) do { \
    WRA1(dst, 0, ga0); WRA1(dst, 1, ga1); WRA1(dst, 2, ga2); WRA1(dst, 3, ga3); \
} while (0)

#define STAGE_B(dst, kt) do { \
    _Pragma("unroll") \
    for (int i_ = 0; i_ < 3; i_++) { \
        if (i_ < 2 || tid < 128) { \
            int g_ = (i_ < 2) ? (i_ * 512 + tid) : (1024 + tid); \
            const short* gp_ = Wswz + (size_t)((g_ >> 6) * 64 + (kt)) * 512 + (g_ & 63) * 8; \
            char* lp_ = (dst) + g_ * 16; \
            __builtin_amdgcn_global_load_lds((const __attribute__((address_space(1))) void*)gp_, \
                (__attribute__((address_space(3))) void*)lp_, 16, 0, 0); \
        } \
    } \
    SB0(); \
} while (0)

#define COMPUTE(Abase, Bb) do { \
    short8 af0_ = *(const short8*)((Abase) + (wsub * 2 + 0) * 1024 + lane * 16); \
    short8 af1_ = *(const short8*)((Abase) + (wsub * 2 + 1) * 1024 + lane * 16); \
    _Pragma("unroll") \
    for (int n_ = 0; n_ < 9; n_++) { \
        short8 bf_ = *(const short8*)((Bb) + (nhalf * 9 + n_) * 1024 + lane * 16); \
        acc0[n_] = __builtin_amdgcn_mfma_f32_16x16x32_bf16(af0_, bf_, acc0[n_], 0, 0, 0); \
        acc1[n_] = __builtin_amdgcn_mfma_f32_16x16x32_bf16(af1_, bf_, acc1[n_], 0, 0, 0); \
    } \
} while (0)

    LOADA4(0);
    WRITEA4(lds);
    STAGE_B(B0, 0);
    LOADA4(1);
    __syncthreads();

    #pragma unroll 1
    for (int g = 0; g < 16; g++) {
        const int t0 = g * 4;
        char* Ac = lds + (g & 1) * A_GRP;
        char* An = lds + ((g & 1) ^ 1) * A_GRP;
        if (g < 15) WRITEA4(An);
        STAGE_B(B1, t0 + 1);
        if (kph == 0) COMPUTE(Ac, B0);
        __syncthreads();
        if (g < 14) LOADA4(g + 2);
        STAGE_B(B0, t0 + 2);
        if (kph == 1) COMPUTE(Ac + 4096, B1);
        __syncthreads();
        STAGE_B(B1, t0 + 3);
        if (kph == 0) COMPUTE(Ac + 8192, B0);
        __syncthreads();
        if (g < 15) STAGE_B(B0, t0 + 4);
        if (kph == 1) COMPUTE(Ac + 12288, B1);
        __syncthreads();
    }

#undef LOADA4
#undef WRITEA4
#undef COMPUTE

#define RED_PHASE(ACC, MOFS) do { \
    __syncthreads(); \
    if (kph == 1) { \
        char* dst_ = lds + (wave & 3) * 9216; \
        _Pragma("unroll") \
        for (int n_ = 0; n_ < 9; n_++) \
            *(f32x4*)(dst_ + (n_ * 64 + lane) * 16) = ACC[n_]; \
    } \
    __syncthreads(); \
    if (kph == 0) { \
        const char* src_ = lds + wave * 9216; \
        _Pragma("unroll") \
        for (int n_ = 0; n_ < 9; n_++) { \
            f32x4 p_ = *(const f32x4*)(src_ + (n_ * 64 + lane) * 16); \
            int c_ = nhalf * 144 + n_ * 16 + l15; \
            if (c_ < NCOLS) { \
                float bv_ = bias[c_]; \
                int row0_ = rowbase + wsub * 32 + (MOFS) * 16 + lhi * 4; \
                _Pragma("unroll") \
                for (int r_ = 0; r_ < 4; r_++) \
                    logits[(size_t)(row0_ + r_) * NCOLS + c_] = ACC[n_][r_] + p_[r_] + bv_; \
            } \
        } \
    } \
} while (0)

    RED_PHASE(acc0, 0);
    RED_PHASE(acc1, 1);
#undef RED_PHASE
#undef WRA1
#undef STAGE_B
}

// ---------------------------------------------------------------------------
// Loss (unchanged)
// ---------------------------------------------------------------------------
__global__ __launch_bounds__(256)
void mvh_loss(const float* __restrict__ logits, const int* __restrict__ labels,
              float* __restrict__ loss_out) {
    int gid = blockIdx.x * 256 + threadIdx.x;
    const float* p = logits + (size_t)gid * 10;
    float x[10];
    #pragma unroll
    for (int j = 0; j < 10; j++) x[j] = p[j];
    float m = x[0];
    #pragma unroll
    for (int j = 1; j < 10; j++) m = fmaxf(m, x[j]);
    float s = 0.0f;
    #pragma unroll
    for (int j = 0; j < 10; j++) s += __expf(x[j] - m);
    int lab = labels[gid];
    float xl = x[0];
    #pragma unroll
    for (int j = 1; j < 10; j++) xl = (lab == j) ? x[j] : xl;
    float nll = m + __logf(s) - xl;

    #pragma unroll
    for (int off = 32; off > 0; off >>= 1)
        nll += __shfl_down(nll, off, 64);

    __shared__ float part[4];
    int lane = threadIdx.x & 63, wv = threadIdx.x >> 6;
    if (lane == 0) part[wv] = nll;
    __syncthreads();
    if (threadIdx.x == 0)
        atomicAdd(loss_out, (part[0] + part[1] + part[2] + part[3]) * LOSS_SCALE);
}

// ---------------------------------------------------------------------------
// DIAGNOSTIC 1: best-case linear HBM read BW over `hidden`.
// 4 passes x 268 MB = 1.07 GB read. 2048 blocks x 256 thr, f32x4 grid-stride.
// Writes only to d_ws sink. Expect ~170 µs @6.3 TB/s; ~480 µs @2.2 TB/s.
// ---------------------------------------------------------------------------
__global__ __launch_bounds__(256)
void mvh_abench1(const float* __restrict__ hidden, f32x4* __restrict__ sink) {
    const size_t total  = (size_t)BATCH * DIM / 4;   // 16,777,216 f32x4
    const size_t stride = (size_t)2048 * 256;
    size_t gid = (size_t)blockIdx.x * 256 + threadIdx.x;
    const f32x4* p = (const f32x4*)hidden;
    f32x4 s = (f32x4)0.0f;
    #pragma unroll 1
    for (int pass = 0; pass < 4; pass++) {
        #pragma unroll 8
        for (size_t i = gid; i < total; i += stride) s += p[i];
    }
    sink[gid] = s;
}

// ---------------------------------------------------------------------------
// DIAGNOSTIC 2: R8 staging skeleton x3 (A reg-load + cvt + LDS write, B DMA,
// identical barrier cadence), NO ds_read / NO MFMA. 48 groups = 192 tiles.
// Expect ~3x the gemm's staging cost. Writes only to d_ws sink.
// ---------------------------------------------------------------------------
__global__ __launch_bounds__(512, 4)
void mvh_abench2(const float* __restrict__ hidden, const short* __restrict__ Wswz,
                 float* __restrict__ sink) {
    __shared__ __align__(16) char lds[2 * A_GRP + 2 * B_TILE];
    char* B0 = lds + 2 * A_GRP;
    char* B1 = lds + 2 * A_GRP + B_TILE;

    const int tid = threadIdx.x;
    const int rowbase = blockIdx.x * 64;
    const int ar  = tid >> 3;
    const int ak4 = (tid & 7) * 4;
    const float* gAbase = hidden + (size_t)(rowbase + ar) * DIM + ak4;
    const int awbyte = (ar >> 4) * 1024 + ((ar & 15) + 16 * (ak4 >> 3)) * 16 + (ak4 & 4) * 2;

    f32x4 ga0, ga1, ga2, ga3;

#define LOADA4B(grp) do { \
    const float* p_ = gAbase + (size_t)((grp) & 15) * 128; \
    ga0 = *(const f32x4*)(p_);      ga1 = *(const f32x4*)(p_ + 32); \
    ga2 = *(const f32x4*)(p_ + 64); ga3 = *(const f32x4*)(p_ + 96); \
    SB0(); \
} while (0)

#define WRA1B(dst, slot, src) do { \
    s4vec w_; \
    w_[0] = f2bf(src[0]); w_[1] = f2bf(src[1]); w_[2] = f2bf(src[2]); w_[3] = f2bf(src[3]); \
    *(s4vec*)((dst) + (slot) * 4096 + awbyte) = w_; \
} while (0)

#define WRITEA4B(dst) do { \
    WRA1B(dst, 0, ga0); WRA1B(dst, 1, ga1); WRA1B(dst, 2, ga2); WRA1B(dst, 3, ga3); \
} while (0)

#define STAGE_BB(dst, kt) do { \
    _Pragma("unroll") \
    for (int i_ = 0; i_ < 3; i_++) { \
        if (i_ < 2 || tid < 128) { \
            int g_ = (i_ < 2) ? (i_ * 512 + tid) : (1024 + tid); \
            const short* gp_ = Wswz + (size_t)((g_ >> 6) * 64 + ((kt) & 63)) * 512 + (g_ & 63) * 8; \
            char* lp_ = (dst) + g_ * 16; \
            __builtin_amdgcn_global_load_lds((const __attribute__((address_space(1))) void*)gp_, \
                (__attribute__((address_space(3))) void*)lp_, 16, 0, 0); \
        } \
    } \
    SB0(); \
} while (0)

    LOADA4B(0);
    WRITEA4B(lds);
    STAGE_BB(B0, 0);
    LOADA4B(1);
    __syncthreads();

    #pragma unroll 1
    for (int g = 0; g < 48; g++) {
        const int t0 = g * 4;
        char* An = lds + ((g & 1) ^ 1) * A_GRP;
        WRITEA4B(An);
        STAGE_BB(B1, t0 + 1);
        __syncthreads();
        LOADA4B(g + 2);
        STAGE_BB(B0, t0 + 2);
        __syncthreads();
        STAGE_BB(B1, t0 + 3);
        __syncthreads();
        STAGE_BB(B0, t0 + 4);
        __syncthreads();
    }

#undef LOADA4B
#undef WRA1B
#undef WRITEA4B
#undef STAGE_BB

    // keep LDS state live (defeat dead-store elim)
    float v = *(const float*)(lds + tid * 64);
    sink[(size_t)blockIdx.x * 512 + tid] = v + ga0[0] + ga1[0] + ga2[0] + ga3[0];
}

extern "C" void kernel_launch(void* const* d_in, const int* in_sizes, int n_in,
                              void* d_out, int out_size, void* d_ws, size_t ws_size,
                              hipStream_t stream) {
    const float* hidden = (const float*)d_in[0];
    const int* labels   = (const int*)d_in[1];
    const float* W      = (const float*)d_in[2];
    const float* bias   = (const float*)d_in[3];
    float* out = (float*)d_out;
    short* Wswz = (short*)d_ws;                                   // 1.18 MB
    f32x4* sink1 = (f32x4*)((char*)d_ws + (16u << 20));           // 8.4 MB
    float* sink2 = (float*)((char*)d_ws + (32u << 20));           // 1.05 MB

    (void)hipMemsetAsync(d_out, 0, sizeof(float), stream);        // zero loss accumulator
    mvh_swz<<<288, 256, 0, stream>>>(W, Wswz);
    mvh_gemm<<<512, 512, 0, stream>>>(hidden, Wswz, bias, out + 1);
    mvh_loss<<<3584, 256, 0, stream>>>(out + 1, labels, out);
    // --- diagnostics (write only to d_ws; product output unaffected) ---
    mvh_abench1<<<2048, 256, 0, stream>>>(hidden, sink1);
    mvh_abench2<<<512, 512, 0, stream>>>(hidden, Wswz, sink2);
}

// Round 10
// 139.975 us; speedup vs baseline: 3.3396x; 3.3396x over previous
//
#include <hip/hip_runtime.h>
#include <hip/hip_bf16.h>

#define BATCH   32768
#define DIM     2048
#define NHEADS  28
#define NCOLS   280
#define LOSS_SCALE (1.0f / (float)(BATCH * NHEADS))

typedef __attribute__((ext_vector_type(8))) short short8;
typedef __attribute__((ext_vector_type(4))) float f32x4;
typedef __attribute__((ext_vector_type(16))) float f32x16;

__device__ __forceinline__ short f2bf(float f) {
    union { __hip_bfloat16 h; short s; } u; u.h = __float2bfloat16(f); return u.s;
}

// ---------------------------------------------------------------------------
// W pre-swizzle: W [280][2048] f32 -> Wswz bf16 in 32x32x16 B-frag order,
// K-tile-major (per-tile 20KB contiguous):
//   short idx = kt*10240 + g*8 + j,  g = (nt*2+ks)*64 + l
//   n = nt*32 + (l&31), k = kt*32 + ks*16 + (l>>5)*8 + j
// 64 kt x 10 nt x 2 ks x 64 lanes x 8 = 655360 shorts (1.31 MB).
// ---------------------------------------------------------------------------
__global__ void mvh_swz(const float* __restrict__ W, short* __restrict__ Wswz) {
    int t = blockIdx.x * 256 + threadIdx.x;      // 81920 threads (320 blocks)
    int kt = t / 1280;
    int r  = t - kt * 1280;                      // 0..1279
    int F  = r >> 6;                             // 0..19
    int nt = F >> 1;
    int ks = F & 1;
    int l  = t & 63;
    int n = nt * 32 + (l & 31);
    int k = kt * 32 + ks * 16 + (l >> 5) * 8;
    short8 v;
    #pragma unroll
    for (int j = 0; j < 8; j++) v[j] = 0;
    if (n < NCOLS) {
        const float* src = W + (size_t)n * DIM + k;
        #pragma unroll
        for (int j = 0; j < 8; j++) v[j] = f2bf(src[j]);
    }
    *(short8*)(Wswz + (size_t)t * 8) = v;
}

// ---------------------------------------------------------------------------
// GEMM: logits[b][n] = sum_d hidden[b][d]*W[n][d] + bias[n]
// grid 256 x 512 threads (8 waves), 1 block/CU. BM=128, BK=32, 64 K-tiles.
// MFMA 32x32x16 (2x FLOP per LDS byte vs 16x16x32). N padded to 320.
// Wave = 32 rows (wsub=w>>1) x 160 cols (nh=w&1, 5 frags); acc 5 x f32x16.
// A (fp32) AND B (bf16) both staged by global_load_lds into 3-buffer
// rotation: tile s+2 issued during segment s, drained (counted per-wave
// vmcnt, never 0) at end of segment s+1 -> wait-distance ~2 segments.
// Raw s_barrier only; NO ds_writes, NO lgkm drains, NO vmcnt(0) in loop.
// ---------------------------------------------------------------------------
#define A_T 16384                    // 128 rows x 32 k x 4B, frag-major
#define B_T 20480                    // 10 nt x 2 ks x 1KB frags
#define AOFF(b) ((b) * A_T)
#define BOFF(b) (3 * A_T + (b) * B_T)

#define SB0() __builtin_amdgcn_sched_barrier(0)
#define GLOAD(src, dst) __builtin_amdgcn_global_load_lds( \
    (const __attribute__((address_space(1))) void*)(src), \
    (__attribute__((address_space(3))) void*)(dst), 16, 0, 0)

__global__ __launch_bounds__(512, 2)
void mvh_gemm(const float* __restrict__ hidden, const short* __restrict__ Wswz,
              const float* __restrict__ bias, float* __restrict__ logits) {
    __shared__ __align__(16) char lds[3 * A_T + 3 * B_T];   // 110592 B

    const int tid  = threadIdx.x;
    const int lane = tid & 63;
    const int wave = tid >> 6;          // 0..7
    const int wsub = wave >> 1;         // 0..3: 32-row frag
    const int nh   = wave & 1;          // 0..1: 5-frag col half
    const int rowbase = blockIdx.x * 128;

    // A-DMA source for granule g: fa=g>>8, ks=(g>>7)&1, p=(g>>6)&1, l=g&63
    //   row = rowbase + fa*32 + (l&31); k = kt*32 + ks*16 + (l>>5)*8 + p*4
    const int g1 = 512 + tid;
    const int row0 = rowbase + ((tid >> 8) << 5) + (lane & 31);
    const int kk0  = ((tid >> 7) & 1) * 16 + (lane >> 5) * 8 + ((tid >> 6) & 1) * 4;
    const int row1 = rowbase + ((g1 >> 8) << 5) + (lane & 31);
    const int kk1  = ((g1 >> 7) & 1) * 16 + (lane >> 5) * 8 + ((g1 >> 6) & 1) * 4;
    const float* gA0 = hidden + (size_t)row0 * DIM + kk0;
    const float* gA1 = hidden + (size_t)row1 * DIM + kk1;

    f32x16 acc[5];
    #pragma unroll
    for (int nf = 0; nf < 5; nf++)
        #pragma unroll
        for (int r = 0; r < 16; r++) acc[nf][r] = 0.0f;

#define STAGE_A(dstoff, kt) do { \
    GLOAD(gA0 + (kt) * 32, lds + (dstoff) + tid * 16); \
    GLOAD(gA1 + (kt) * 32, lds + (dstoff) + 8192 + tid * 16); \
} while (0)

#define STAGE_B(dstoff, kt) do { \
    const short* bp_ = Wswz + (size_t)(kt) * 10240; \
    GLOAD(bp_ + tid * 8,          lds + (dstoff) + tid * 16); \
    GLOAD(bp_ + (512 + tid) * 8,  lds + (dstoff) + 8192 + tid * 16); \
    if (tid < 256) GLOAD(bp_ + (1024 + tid) * 8, lds + (dstoff) + 16384 + tid * 16); \
} while (0)

    // waves 0-3 issue 5 loads/segment (2A+3B), waves 4-7 issue 4 (2A+2B).
    // Keep this segment's issues in flight; drain last segment's.
#define WAITP() do { \
    if (wave < 4) { asm volatile("s_waitcnt vmcnt(5)" ::: "memory"); } \
    else          { asm volatile("s_waitcnt vmcnt(4)" ::: "memory"); } \
    SB0(); \
} while (0)

#define COMPUTE(aoff, boff) do { \
    _Pragma("unroll") \
    for (int ks_ = 0; ks_ < 2; ks_++) { \
        f32x4 lo_ = *(const f32x4*)(lds + (aoff) + ((wsub * 2 + ks_) * 2 + 0) * 1024 + lane * 16); \
        f32x4 hi_ = *(const f32x4*)(lds + (aoff) + ((wsub * 2 + ks_) * 2 + 1) * 1024 + lane * 16); \
        short8 af_; \
        _Pragma("unroll") \
        for (int j_ = 0; j_ < 4; j_++) { af_[j_] = f2bf(lo_[j_]); af_[4 + j_] = f2bf(hi_[j_]); } \
        _Pragma("unroll") \
        for (int nf_ = 0; nf_ < 5; nf_++) { \
            short8 bf_ = *(const short8*)(lds + (boff) + ((nh * 5 + nf_) * 2 + ks_) * 1024 + lane * 16); \
            acc[nf_] = __builtin_amdgcn_mfma_f32_32x32x16_bf16(af_, bf_, acc[nf_], 0, 0, 0); \
        } \
    } \
} while (0)

#define SEG(tile, cb, stb) do { \
    STAGE_A(AOFF(stb), (tile) + 2); \
    STAGE_B(BOFF(stb), (tile) + 2); \
    SB0(); \
    COMPUTE(AOFF(cb), BOFF(cb)); \
    WAITP(); \
    __builtin_amdgcn_s_barrier(); \
    SB0(); \
} while (0)

    // ---- prologue: stage tiles 0,1 -> bufs 0,1; drain tile 0 only ----
    STAGE_A(AOFF(0), 0); STAGE_B(BOFF(0), 0);
    STAGE_A(AOFF(1), 1); STAGE_B(BOFF(1), 1);
    WAITP();
    __builtin_amdgcn_s_barrier();
    SB0();

    // ---- main: 3-buffer rotation, stage s+2 in segment s ----
    #pragma unroll 1
    for (int sb = 0; sb < 60; sb += 3) {
        SEG(sb + 0, 0, 2);
        SEG(sb + 1, 1, 0);
        SEG(sb + 2, 2, 1);
    }
    SEG(60, 0, 2);           // stages tile 62 -> buf 2
    SEG(61, 1, 0);           // stages tile 63 -> buf 0
    // segment 62: compute buf 2; drain tile 63
    COMPUTE(AOFF(2), BOFF(2));
    asm volatile("s_waitcnt vmcnt(0)" ::: "memory");
    __builtin_amdgcn_s_barrier();
    SB0();
    // segment 63
    COMPUTE(AOFF(0), BOFF(0));

#undef SEG
#undef COMPUTE
#undef WAITP
#undef STAGE_A
#undef STAGE_B

    // ---- epilogue: bias + store ----
    // C/D 32x32: col = lane&31, row = (reg&3) + 8*(reg>>2) + 4*(lane>>5)
    #pragma unroll
    for (int nf = 0; nf < 5; nf++) {
        int c = (nh * 5 + nf) * 32 + (lane & 31);
        if (c < NCOLS) {
            float bv = bias[c];
            #pragma unroll
            for (int r = 0; r < 16; r++) {
                int row = rowbase + wsub * 32 + (r & 3) + 8 * (r >> 2) + 4 * (lane >> 5);
                logits[(size_t)row * NCOLS + c] = acc[nf][r] + bv;
            }
        }
    }
}

// ---------------------------------------------------------------------------
// Loss: one thread per (row, head). nll = logsumexp(10) - x[label].
// ---------------------------------------------------------------------------
__global__ __launch_bounds__(256)
void mvh_loss(const float* __restrict__ logits, const int* __restrict__ labels,
              float* __restrict__ loss_out) {
    int gid = blockIdx.x * 256 + threadIdx.x;    // 917504 = 3584*256 exactly
    const float* p = logits + (size_t)gid * 10;
    float x[10];
    #pragma unroll
    for (int j = 0; j < 10; j++) x[j] = p[j];
    float m = x[0];
    #pragma unroll
    for (int j = 1; j < 10; j++) m = fmaxf(m, x[j]);
    float s = 0.0f;
    #pragma unroll
    for (int j = 0; j < 10; j++) s += __expf(x[j] - m);
    int lab = labels[gid];
    float xl = x[0];
    #pragma unroll
    for (int j = 1; j < 10; j++) xl = (lab == j) ? x[j] : xl;
    float nll = m + __logf(s) - xl;

    #pragma unroll
    for (int off = 32; off > 0; off >>= 1)
        nll += __shfl_down(nll, off, 64);

    __shared__ float part[4];
    int lane = threadIdx.x & 63, wv = threadIdx.x >> 6;
    if (lane == 0) part[wv] = nll;
    __syncthreads();
    if (threadIdx.x == 0)
        atomicAdd(loss_out, (part[0] + part[1] + part[2] + part[3]) * LOSS_SCALE);
}

extern "C" void kernel_launch(void* const* d_in, const int* in_sizes, int n_in,
                              void* d_out, int out_size, void* d_ws, size_t ws_size,
                              hipStream_t stream) {
    const float* hidden = (const float*)d_in[0];
    const int* labels   = (const int*)d_in[1];
    const float* W      = (const float*)d_in[2];
    const float* bias   = (const float*)d_in[3];
    float* out = (float*)d_out;
    short* Wswz = (short*)d_ws;   // 655360 bf16 = 1.31 MB

    (void)hipMemsetAsync(d_out, 0, sizeof(float), stream);     // zero loss accumulator
    mvh_swz<<<320, 256, 0, stream>>>(W, Wswz);
    mvh_gemm<<<256, 512, 0, stream>>>(hidden, Wswz, bias, out + 1);
    mvh_loss<<<3584, 256, 0, stream>>>(out + 1, labels, out);
}